// Round 7
// baseline (664.651 us; speedup 1.0000x reference)
//
#include <hip/hip_runtime.h>

#define NATOMS 768
#define NM1    767
#define NEDGE  (768*767)       // 589056
#define DIM    64
#define NC     50
#define GAPF   (5.0f/49.0f)
#define NIGAP  (-49.0f/5.0f)
#define G      512
#define STEPF  (5.0f/511.0f)
#define INVSTEP (511.0f/5.0f)
#define LN2F   0.693147180559945f

// ws layout (float offsets)
#define WS_H     0              // 768*64
#define WS_NWA   49152          // 768*64 (layer0 input, written by k_pre)
#define WS_NWB   98304          // 768*64 (layer1 input)
#define WS_NWC   147456         // 768*64 (layer2 input)
#define WS_HA    196608         // 768
#define WS_CTR   197376         // 8 uints (barrier counters)
#define WS_DISTT 197632         // 768*768
#define WS_TT    787456         // 4 tables * 512*64 float2 = 262144 floats

__device__ __forceinline__ float softplus05(float x) {
    float bx = 0.5f * x;
    return (bx > 14.0f) ? x : 2.0f * __logf(1.0f + __expf(bx));
}
__device__ __forceinline__ int lane_bcast_i(int v, int l) {
    return __builtin_amdgcn_readlane(v, l);
}
__device__ __forceinline__ float lane_bcast_f(float v, int l) {
    return __uint_as_float((unsigned)__builtin_amdgcn_readlane((int)__float_as_uint(v), l));
}

// ============ prologue: tables(G=512) + embed/nw0 + dist transpose ============
// (verbatim round-5 proven kernel + barrier-counter zeroing)
__global__ __launch_bounds__(256)
void k_pre(const int* __restrict__ types, const float* __restrict__ dist,
           const float* __restrict__ emb, const float* __restrict__ w1all,
           const float* __restrict__ pw1, const float* __restrict__ pb1,
           const float* __restrict__ pw2, const float* __restrict__ pb2,
           const float* __restrict__ row1, const float* __restrict__ rob1,
           float* __restrict__ ws) {
    __shared__ float s_t[4 * 64];
    const int tid = threadIdx.x, widx = tid >> 6, c = tid & 63;
    float* h     = ws + WS_H;
    float* nw    = ws + WS_NWA;
    float* distT = ws + WS_DISTT;
    float* TTf   = ws + WS_TT;
    const int b = blockIdx.x;

    if (b == 0 && tid < 8) ((unsigned*)(ws + WS_CTR))[tid] = 0u;

    if (b < 512) {
        const int w = b * 4 + widx, tbl = w >> 9, g = w & 511;
        const float d = g * STEPF;
        float val;
        if (tbl < 3) {
            const float* W1 = pw1 + tbl * NC * DIM;
            float t1 = pb1[tbl * DIM + c];
            for (int k = 0; k < NC; ++k) {
                float x = d - GAPF * (float)k;
                t1 = fmaf(__expf(NIGAP * x * x), W1[k * DIM + c], t1);
            }
            s_t[widx * 64 + c] = softplus05(t1);     // wave-local lockstep
            const float* W2 = pw2 + tbl * DIM * DIM;
            val = pb2[tbl * DIM + c];
            #pragma unroll 8
            for (int k = 0; k < DIM; ++k)
                val = fmaf(s_t[widx * 64 + k], W2[k * DIM + c], val);
        } else {
            val = rob1[c];
            for (int k = 0; k < NC; ++k) {
                float x = d - GAPF * (float)k;
                val = fmaf(__expf(NIGAP * x * x), row1[(2 + k) * DIM + c], val);
            }
        }
        // paired layout: row g holds (T[g][c], T[g+1][c]) as float2
        float* TTt = TTf + tbl * (G * DIM * 2);
        TTt[(g * DIM + c) * 2] = val;
        if (g > 0) TTt[((g - 1) * DIM + c) * 2 + 1] = val;
    } else if (b < 704) {
        const int i = (b - 512) * 4 + widx;
        float hv = emb[types[i] * DIM + c];
        h[i * DIM + c] = hv;
        s_t[widx * 64 + c] = hv;                     // wave-local
        float acc = 0.0f;
        #pragma unroll 8
        for (int k = 0; k < DIM; ++k)
            acc = fmaf(s_t[widx * 64 + k], w1all[k * DIM + c], acc);
        nw[i * DIM + c] = acc;
    } else {
        const int idx = (b - 704) * 256 + tid;       // < 768*768
        const int j = idx / NATOMS, i = idx - j * NATOMS;
        distT[idx] = (i == j) ? 0.0f : dist[i * NM1 + (j - (j > i))];
    }
}

// ============ mega: 3 conv layers + readout, custom grid barriers ============
struct P4s { float4 pre[4][64]; float h[4][16 * 65]; float w2[128]; }; // 21248 B
union SmemM {
    struct { float part[4][64]; float upd[192]; } cv;                 // 1792 B
    P4s p4;
};

__global__ __launch_bounds__(256, 3)
void k_mega(const float* __restrict__ dist, const int* __restrict__ srcI,
            const int* __restrict__ dstI, const float* __restrict__ w1all,
            const float* __restrict__ qw1, const float* __restrict__ qb1,
            const float* __restrict__ qw2, const float* __restrict__ qb2,
            const float* __restrict__ auw1, const float* __restrict__ aub1,
            const float* __restrict__ auw2, const float* __restrict__ aub2,
            const float* __restrict__ row1, const float* __restrict__ row2,
            const float* __restrict__ rob2,
            float* __restrict__ ws, float* __restrict__ out) {
    __shared__ SmemM sm;
    const int tid = threadIdx.x, widx = tid >> 6, c = tid & 63;
    const int b = blockIdx.x;
    float* hG    = ws + WS_H;
    float* ha    = ws + WS_HA;
    unsigned* ctr = (unsigned*)(ws + WS_CTR);
    const float* distT = ws + WS_DISTT;
    const float* TTf   = ws + WS_TT;
    float* nwbuf[3] = { ws + WS_NWA, ws + WS_NWB, ws + WS_NWC };

    float hreg = (widx == 0) ? hG[b * DIM + c] : 0.0f;   // h row lives in wave0 regs

    for (int l = 0; l < 3; ++l) {
        const float* nwin = nwbuf[l];
        const float2* TTl = (const float2*)TTf + l * (G * DIM);
        const char* TTb = (const char*)TTl + c * 8;
        float csum = 0.0f;
        #pragma unroll
        for (int ch = 0; ch < 3; ++ch) {                  // 4 waves x 192 sources
            const int s0 = widx * 192 + ch * 64;
            float d = distT[b * NATOMS + s0 + c];
            float pos = d * INVSTEP;
            int g = (int)pos;
            g = (g < 0) ? 0 : ((g > 510) ? 510 : g);
            float f = pos - (float)g;
            int kx = g * 512;                             // byte offset of row pair
            #pragma unroll 8
            for (int it = 0; it < 64; ++it) {
                int kxu = lane_bcast_i(kx, it);
                float fu = lane_bcast_f(f, it);
                float2 tt = *(const float2*)(TTb + kxu);
                float e = fmaf(fu, tt.y - tt.x, tt.x);
                csum = fmaf(e, nwin[(s0 + it) * DIM + c], csum);
            }
        }
        sm.cv.part[widx][c] = csum;
        __syncthreads();
        if (widx == 0) {
            float tot = sm.cv.part[0][c] + sm.cv.part[1][c]
                      + sm.cv.part[2][c] + sm.cv.part[3][c];
            // remove fake i==j term: distT diag=0 -> e = T[0][c] exactly
            float2 t0 = *(const float2*)TTb;
            tot -= t0.x * nwin[b * DIM + c];
            float* su = sm.cv.upd;                        // wave-local lockstep
            su[c] = tot;
            float t = qb1[l * DIM + c];
            #pragma unroll 8
            for (int k = 0; k < DIM; ++k)
                t = fmaf(su[k], qw1[l * DIM * DIM + k * DIM + c], t);
            su[64 + c] = softplus05(t);
            float o = qb2[l * DIM + c];
            #pragma unroll 8
            for (int k = 0; k < DIM; ++k)
                o = fmaf(su[64 + k], qw2[l * DIM * DIM + k * DIM + c], o);
            hreg += o;
            su[128 + c] = hreg;
            if (l < 2) {
                const float* Wn = w1all + (l + 1) * DIM * DIM;
                float v = 0.0f;
                #pragma unroll 8
                for (int k = 0; k < DIM; ++k) v = fmaf(su[128 + k], Wn[k * DIM + c], v);
                nwbuf[l + 1][b * DIM + c] = v;
            } else {
                float t2 = aub1[c];
                #pragma unroll 8
                for (int k = 0; k < DIM; ++k) t2 = fmaf(su[128 + k], auw1[k * DIM + c], t2);
                t2 = ((t2 > 20.0f) ? t2 : __logf(1.0f + __expf(t2))) - LN2F;
                float v = t2 * auw2[c];
                #pragma unroll
                for (int s = 32; s > 0; s >>= 1) v += __shfl_down(v, s, 64);
                if (c == 0) ha[b] = v + aub2[0];
            }
            // ---- grid barrier l: release own write, wait for all 768 ----
            if (c == 0) {
                __hip_atomic_fetch_add(&ctr[l], 1u, __ATOMIC_ACQ_REL,
                                       __HIP_MEMORY_SCOPE_AGENT);
                unsigned guard = 0;
                while (__hip_atomic_load(&ctr[l], __ATOMIC_ACQUIRE,
                                         __HIP_MEMORY_SCOPE_AGENT) < (unsigned)NATOMS
                       && ++guard < (1u << 24)) { }
            }
        }
        __syncthreads();
    }

    // ---------- readout (round-4-verified phase-4), 3 rounds ----------
    if (tid < 128) sm.p4.w2[tid] = row2[tid];
    __syncthreads();
    const float2* TTro = (const float2*)TTf + 3 * (G * DIM);
    const char* TTb2 = (const char*)TTro + c * 8;
    const float wa = row1[c], wb = row1[DIM + c];
    const int e2 = (c >> 1) & 15, p2 = c & 1, kh = c >> 5;
    const float bias2 = (kh == 0) ? rob2[p2] : 0.0f;
    const int w = b * 4 + widx;
    for (int rnd = 0; rnd < 3; ++rnd) {
        const int w4 = rnd * 3072 + w;               // 9204 tasks cover all edges
        if (w4 >= 9204) break;                       // no barriers below -> safe
        const int ebase = w4 * 64;
        {
            int eg = ebase + c;
            float d = dist[eg];
            float pos = d * INVSTEP;
            int kk = (int)pos;
            kk = (kk < 0) ? 0 : ((kk > 510) ? 510 : kk);
            float fa = ha[srcI[eg]], fb = ha[dstI[eg]];
            sm.p4.pre[widx][c] = make_float4(__int_as_float(kk * 512), pos - (float)kk, fa, fb);
        }
        float* sh = sm.p4.h[widx];
        #pragma unroll
        for (int ch = 0; ch < 4; ++ch) {
            #pragma unroll 4
            for (int e = 0; e < 16; ++e) {           // lane = channel
                float4 p = sm.p4.pre[widx][ch * 16 + e];
                float2 tt = *(const float2*)(TTb2 + __float_as_int(p.x));
                float hv = fmaf(p.y, tt.y - tt.x, tt.x);
                hv = fmaf(p.z, wa, hv);
                hv = fmaf(p.w, wb, hv);
                sh[e * 65 + c] = fmaxf(hv, 0.0f);
            }
            float lsum = bias2;                      // lane = (khalf, edge, logit)
            #pragma unroll 8
            for (int k8 = 0; k8 < 32; ++k8) {
                int k = kh * 32 + k8;
                lsum = fmaf(sh[e2 * 65 + k], sm.p4.w2[2 * k + p2], lsum);
            }
            lsum += __shfl_xor(lsum, 32, 64);
            float other = __shfl_xor(lsum, 1, 64);
            float m = fmaxf(lsum, other);
            float ea = __expf(lsum - m), eb = __expf(other - m);
            float r = ea / (ea + eb);
            if (c < 32) out[ebase * 2 + ch * 32 + c] = r;
        }
    }
}

// ============ fallback: proven round-6 kernels ============
__global__ __launch_bounds__(512)
void k_edgeupd(const float2* __restrict__ TTl, const float* __restrict__ distT,
               const float* __restrict__ nwin,
               const float* __restrict__ qw1, const float* __restrict__ qb1,
               const float* __restrict__ qw2, const float* __restrict__ qb2,
               float* __restrict__ h,
               const float* __restrict__ wnext, float* __restrict__ nwout,
               const float* __restrict__ auw1, const float* __restrict__ aub1,
               const float* __restrict__ auw2, const float* __restrict__ aub2,
               float* __restrict__ ha, int last) {
    __shared__ float s_part[8][64];
    __shared__ float s_upd[192];
    const int tid = threadIdx.x, widx = tid >> 6, c = tid & 63;
    const int j = blockIdx.x;
    const int s0 = widx * 96;
    const char* TTb = (const char*)TTl + c * 8;
    float csum = 0.0f;
    {
        float d = distT[j * NATOMS + s0 + c];
        float pos = d * INVSTEP;
        int g = (int)pos;
        g = (g < 0) ? 0 : ((g > 510) ? 510 : g);
        float f = pos - (float)g;
        int kx = g * 512;
        #pragma unroll 8
        for (int it = 0; it < 64; ++it) {
            int kxu = lane_bcast_i(kx, it);
            float fu = lane_bcast_f(f, it);
            float2 tt = *(const float2*)(TTb + kxu);
            float e = fmaf(fu, tt.y - tt.x, tt.x);
            csum = fmaf(e, nwin[(s0 + it) * DIM + c], csum);
        }
    }
    {
        float d = distT[j * NATOMS + s0 + 64 + (c & 31)];
        float pos = d * INVSTEP;
        int g = (int)pos;
        g = (g < 0) ? 0 : ((g > 510) ? 510 : g);
        float f = pos - (float)g;
        int kx = g * 512;
        #pragma unroll 8
        for (int it = 0; it < 32; ++it) {
            int kxu = lane_bcast_i(kx, it);
            float fu = lane_bcast_f(f, it);
            float2 tt = *(const float2*)(TTb + kxu);
            float e = fmaf(fu, tt.y - tt.x, tt.x);
            csum = fmaf(e, nwin[(s0 + 64 + it) * DIM + c], csum);
        }
    }
    s_part[widx][c] = csum;
    __syncthreads();
    if (widx == 0) {
        float tot = 0.0f;
        #pragma unroll
        for (int w8 = 0; w8 < 8; ++w8) tot += s_part[w8][c];
        float2 t0 = *(const float2*)TTb;
        tot -= t0.x * nwin[j * DIM + c];
        s_upd[c] = tot;
        float t = qb1[c];
        #pragma unroll 8
        for (int k = 0; k < DIM; ++k) t = fmaf(s_upd[k], qw1[k * DIM + c], t);
        s_upd[64 + c] = softplus05(t);
        float o = qb2[c];
        #pragma unroll 8
        for (int k = 0; k < DIM; ++k) o = fmaf(s_upd[64 + k], qw2[k * DIM + c], o);
        float hn = h[j * DIM + c] + o;
        h[j * DIM + c] = hn;
        s_upd[128 + c] = hn;
        if (!last) {
            float v = 0.0f;
            #pragma unroll 8
            for (int k = 0; k < DIM; ++k) v = fmaf(s_upd[128 + k], wnext[k * DIM + c], v);
            nwout[j * DIM + c] = v;
        } else {
            float t2 = aub1[c];
            #pragma unroll 8
            for (int k = 0; k < DIM; ++k) t2 = fmaf(s_upd[128 + k], auw1[k * DIM + c], t2);
            t2 = ((t2 > 20.0f) ? t2 : __logf(1.0f + __expf(t2))) - LN2F;
            float v = t2 * auw2[c];
            #pragma unroll
            for (int s = 32; s > 0; s >>= 1) v += __shfl_down(v, s, 64);
            if (c == 0) ha[j] = v + aub2[0];
        }
    }
}

__global__ __launch_bounds__(256)
void k_ro(const float* __restrict__ dist, const int* __restrict__ src,
          const int* __restrict__ dst, const float* __restrict__ ha,
          const float2* __restrict__ TTro,
          const float* __restrict__ row1, const float* __restrict__ row2,
          const float* __restrict__ rob2, float* __restrict__ out) {
    __shared__ float4 s_pre[4][64];
    __shared__ float s_h[4][16 * 65];
    __shared__ float s_w2[128];
    const int tid = threadIdx.x, widx = tid >> 6, c = tid & 63;
    if (tid < 128) s_w2[tid] = row2[tid];
    __syncthreads();
    const int ebase = (blockIdx.x * 4 + widx) * 64;
    {
        int eg = ebase + c;
        float d = dist[eg];
        float pos = d * INVSTEP;
        int kk = (int)pos;
        kk = (kk < 0) ? 0 : ((kk > 510) ? 510 : kk);
        float fa = ha[src[eg]], fb = ha[dst[eg]];
        s_pre[widx][c] = make_float4(__int_as_float(kk * 512), pos - (float)kk, fa, fb);
    }
    const char* TTb2 = (const char*)TTro + c * 8;
    const float wa = row1[c], wb = row1[DIM + c];
    const int e2 = (c >> 1) & 15, p2 = c & 1, kh = c >> 5;
    const float bias2 = (kh == 0) ? rob2[p2] : 0.0f;
    float* sh = s_h[widx];
    #pragma unroll
    for (int ch = 0; ch < 4; ++ch) {
        #pragma unroll 4
        for (int e = 0; e < 16; ++e) {
            float4 p = s_pre[widx][ch * 16 + e];
            float2 tt = *(const float2*)(TTb2 + __float_as_int(p.x));
            float hv = fmaf(p.y, tt.y - tt.x, tt.x);
            hv = fmaf(p.z, wa, hv);
            hv = fmaf(p.w, wb, hv);
            sh[e * 65 + c] = fmaxf(hv, 0.0f);
        }
        float lsum = bias2;
        #pragma unroll 8
        for (int k8 = 0; k8 < 32; ++k8) {
            int k = kh * 32 + k8;
            lsum = fmaf(sh[e2 * 65 + k], s_w2[2 * k + p2], lsum);
        }
        lsum += __shfl_xor(lsum, 32, 64);
        float other = __shfl_xor(lsum, 1, 64);
        float m = fmaxf(lsum, other);
        float ea = __expf(lsum - m), eb = __expf(other - m);
        float r = ea / (ea + eb);
        if (c < 32) out[ebase * 2 + ch * 32 + c] = r;
    }
}

extern "C" void kernel_launch(void* const* d_in, const int* in_sizes, int n_in,
                              void* d_out, int out_size, void* d_ws, size_t ws_size,
                              hipStream_t stream) {
    const int*   types = (const int*)d_in[0];
    const float* dist  = (const float*)d_in[1];
    const int*   srcI  = (const int*)d_in[2];
    const int*   dstI  = (const int*)d_in[3];
    const float* emb   = (const float*)d_in[4];
    const float* w1    = (const float*)d_in[5];
    const float* pw1   = (const float*)d_in[6];
    const float* pb1   = (const float*)d_in[7];
    const float* pw2   = (const float*)d_in[8];
    const float* pb2   = (const float*)d_in[9];
    const float* qw1   = (const float*)d_in[10];
    const float* qb1   = (const float*)d_in[11];
    const float* qw2   = (const float*)d_in[12];
    const float* qb2   = (const float*)d_in[13];
    const float* auw1  = (const float*)d_in[14];
    const float* aub1  = (const float*)d_in[15];
    const float* auw2  = (const float*)d_in[16];
    const float* aub2  = (const float*)d_in[17];
    const float* row1  = (const float*)d_in[18];
    const float* rob1  = (const float*)d_in[19];
    const float* row2  = (const float*)d_in[20];
    const float* rob2  = (const float*)d_in[21];

    float* ws   = (float*)d_ws;
    float* outp = (float*)d_out;
    const float2* TT = (const float2*)(ws + WS_TT);

    k_pre<<<3008, 256, 0, stream>>>(types, dist, emb, w1, pw1, pb1, pw2, pb2,
                                    row1, rob1, ws);

    // ---- pre-flight: 768-block cooperative launch valid? ----
    int coopOK = 0;
    {
        int dev = 0;
        if (hipGetDevice(&dev) == hipSuccess) {
            hipDeviceProp_t prop;
            if (hipGetDeviceProperties(&prop, dev) == hipSuccess &&
                prop.cooperativeLaunch) {
                int maxB = 0;
                if (hipOccupancyMaxActiveBlocksPerMultiprocessor(
                        &maxB, (const void*)k_mega, 256, 0) == hipSuccess &&
                    (long)maxB * prop.multiProcessorCount >= NATOMS)
                    coopOK = 1;
            }
        }
    }
    if (coopOK) {
        void* args[] = { (void*)&dist, (void*)&srcI, (void*)&dstI, (void*)&w1,
                         (void*)&qw1, (void*)&qb1, (void*)&qw2, (void*)&qb2,
                         (void*)&auw1, (void*)&aub1, (void*)&auw2, (void*)&aub2,
                         (void*)&row1, (void*)&row2, (void*)&rob2,
                         (void*)&ws, (void*)&outp };
        if (hipLaunchCooperativeKernel((void*)k_mega, dim3(NATOMS), dim3(256),
                                       args, 0, stream) == hipSuccess)
            return;
    }

    // ---- fallback: proven round-6 path ----
    float* nwbuf[2] = { ws + WS_NWA, ws + WS_NWB };
    for (int l = 0; l < 3; ++l) {
        k_edgeupd<<<768, 512, 0, stream>>>(TT + l * (G * DIM),
            ws + WS_DISTT, nwbuf[l & 1],
            qw1 + l * DIM * DIM, qb1 + l * DIM,
            qw2 + l * DIM * DIM, qb2 + l * DIM,
            ws + WS_H,
            (l < 2) ? (w1 + (l + 1) * DIM * DIM) : w1, nwbuf[(l + 1) & 1],
            auw1, aub1, auw2, aub2, ws + WS_HA, (l == 2) ? 1 : 0);
    }
    k_ro<<<2301, 256, 0, stream>>>(dist, srcI, dstI, ws + WS_HA, TT + 3 * (G * DIM),
                                   row1, row2, rob2, outp);
}

// Round 8
// 222.234 us; speedup vs baseline: 2.9908x; 2.9908x over previous
//
#include <hip/hip_runtime.h>

#define NATOMS 768
#define NM1    767
#define NEDGE  (768*767)       // 589056
#define DIM    64
#define NC     50
#define GAPF   (5.0f/49.0f)
#define NIGAP  (-49.0f/5.0f)
#define G      512
#define STEPF  (5.0f/511.0f)
#define INVSTEP (511.0f/5.0f)
#define LN2F   0.693147180559945f

// ws layout (float offsets)
#define WS_H     0              // 768*64
#define WS_NWA   49152          // 768*64  (nw ping)
#define WS_NWB   98304          // 768*64  (nw pong)
#define WS_HA    147456         // 768
#define WS_DISTT 148224         // 768*768
#define WS_TT    738048         // 4 tables * 512*64 float2 = 262144 floats

__device__ __forceinline__ float softplus05(float x) {
    float bx = 0.5f * x;
    return (bx > 14.0f) ? x : 2.0f * __logf(1.0f + __expf(bx));
}
__device__ __forceinline__ int lane_bcast_i(int v, int l) {
    return __builtin_amdgcn_readlane(v, l);
}
__device__ __forceinline__ float lane_bcast_f(float v, int l) {
    return __uint_as_float((unsigned)__builtin_amdgcn_readlane((int)__float_as_uint(v), l));
}

// ============ prologue: tables(G=512) + embed/nw0 + dist transpose ============
// (verbatim round-5/6 proven kernel)
__global__ __launch_bounds__(256)
void k_pre(const int* __restrict__ types, const float* __restrict__ dist,
           const float* __restrict__ emb, const float* __restrict__ w1all,
           const float* __restrict__ pw1, const float* __restrict__ pb1,
           const float* __restrict__ pw2, const float* __restrict__ pb2,
           const float* __restrict__ row1, const float* __restrict__ rob1,
           float* __restrict__ ws) {
    __shared__ float s_t[4 * 64];
    const int tid = threadIdx.x, widx = tid >> 6, c = tid & 63;
    float* h     = ws + WS_H;
    float* nw    = ws + WS_NWA;
    float* distT = ws + WS_DISTT;
    float* TTf   = ws + WS_TT;
    const int b = blockIdx.x;

    if (b < 512) {
        const int w = b * 4 + widx, tbl = w >> 9, g = w & 511;
        const float d = g * STEPF;
        float val;
        if (tbl < 3) {
            const float* W1 = pw1 + tbl * NC * DIM;
            float t1 = pb1[tbl * DIM + c];
            for (int k = 0; k < NC; ++k) {
                float x = d - GAPF * (float)k;
                t1 = fmaf(__expf(NIGAP * x * x), W1[k * DIM + c], t1);
            }
            s_t[widx * 64 + c] = softplus05(t1);     // wave-local lockstep
            const float* W2 = pw2 + tbl * DIM * DIM;
            val = pb2[tbl * DIM + c];
            #pragma unroll 8
            for (int k = 0; k < DIM; ++k)
                val = fmaf(s_t[widx * 64 + k], W2[k * DIM + c], val);
        } else {
            val = rob1[c];
            for (int k = 0; k < NC; ++k) {
                float x = d - GAPF * (float)k;
                val = fmaf(__expf(NIGAP * x * x), row1[(2 + k) * DIM + c], val);
            }
        }
        // paired layout: row g holds (T[g][c], T[g+1][c]) as float2
        float* TTt = TTf + tbl * (G * DIM * 2);
        TTt[(g * DIM + c) * 2] = val;
        if (g > 0) TTt[((g - 1) * DIM + c) * 2 + 1] = val;
    } else if (b < 704) {
        const int i = (b - 512) * 4 + widx;
        float hv = emb[types[i] * DIM + c];
        h[i * DIM + c] = hv;
        s_t[widx * 64 + c] = hv;                     // wave-local
        float acc = 0.0f;
        #pragma unroll 8
        for (int k = 0; k < DIM; ++k)
            acc = fmaf(s_t[widx * 64 + k], w1all[k * DIM + c], acc);
        nw[i * DIM + c] = acc;
    } else {
        const int idx = (b - 704) * 256 + tid;       // < 768*768
        const int j = idx / NATOMS, i = idx - j * NATOMS;
        distT[idx] = (i == j) ? 0.0f : dist[i * NM1 + (j - (j > i))];
    }
}

// ============ conv layer: block owns dest-TRIPLE (3b,3b+1,3b+2) ============
// 256 blocks x 8 waves; wave widx covers sources [widx*96, widx*96+96).
// Each nw row read serves 3 dests (192 MACs / 1792 B). Partials combined
// in LDS; waves 0..2 run the node MLP for their dest.
__global__ __launch_bounds__(512)
void k_edgeupd3(const float2* __restrict__ TTl, const float* __restrict__ distT,
                const float* __restrict__ nwin,
                const float* __restrict__ qw1, const float* __restrict__ qb1,
                const float* __restrict__ qw2, const float* __restrict__ qb2,
                float* __restrict__ h,
                const float* __restrict__ wnext, float* __restrict__ nwout,
                const float* __restrict__ auw1, const float* __restrict__ aub1,
                const float* __restrict__ auw2, const float* __restrict__ aub2,
                float* __restrict__ ha, int last) {
    __shared__ float s_part[8][3][64];
    __shared__ float s_upd[3][192];
    const int tid = threadIdx.x, widx = tid >> 6, c = tid & 63;
    const int j0 = blockIdx.x * 3;
    const int s0 = widx * 96;

    const char* TTb = (const char*)TTl + c * 8;
    float acc0 = 0.0f, acc1 = 0.0f, acc2 = 0.0f;

    { // ---- chunk A: sources s0 .. s0+63 ----
        float dA = distT[j0 * NATOMS + s0 + c];
        float dB = distT[(j0 + 1) * NATOMS + s0 + c];
        float dC = distT[(j0 + 2) * NATOMS + s0 + c];
        float pA = dA * INVSTEP, pB = dB * INVSTEP, pC = dC * INVSTEP;
        int gA = (int)pA, gB = (int)pB, gC = (int)pC;
        gA = (gA < 0) ? 0 : ((gA > 510) ? 510 : gA);
        gB = (gB < 0) ? 0 : ((gB > 510) ? 510 : gB);
        gC = (gC < 0) ? 0 : ((gC > 510) ? 510 : gC);
        float fA = pA - (float)gA, fB = pB - (float)gB, fC = pC - (float)gC;
        int kA = gA * 512, kB = gB * 512, kC = gC * 512;
        #pragma unroll 8
        for (int it = 0; it < 64; ++it) {
            float nwv = nwin[(s0 + it) * DIM + c];
            {
                float2 tt = *(const float2*)(TTb + lane_bcast_i(kA, it));
                float e = fmaf(lane_bcast_f(fA, it), tt.y - tt.x, tt.x);
                acc0 = fmaf(e, nwv, acc0);
            }
            {
                float2 tt = *(const float2*)(TTb + lane_bcast_i(kB, it));
                float e = fmaf(lane_bcast_f(fB, it), tt.y - tt.x, tt.x);
                acc1 = fmaf(e, nwv, acc1);
            }
            {
                float2 tt = *(const float2*)(TTb + lane_bcast_i(kC, it));
                float e = fmaf(lane_bcast_f(fC, it), tt.y - tt.x, tt.x);
                acc2 = fmaf(e, nwv, acc2);
            }
        }
    }
    { // ---- chunk B: sources s0+64 .. s0+95 (32), lanes mirrored via c&31 ----
        float dA = distT[j0 * NATOMS + s0 + 64 + (c & 31)];
        float dB = distT[(j0 + 1) * NATOMS + s0 + 64 + (c & 31)];
        float dC = distT[(j0 + 2) * NATOMS + s0 + 64 + (c & 31)];
        float pA = dA * INVSTEP, pB = dB * INVSTEP, pC = dC * INVSTEP;
        int gA = (int)pA, gB = (int)pB, gC = (int)pC;
        gA = (gA < 0) ? 0 : ((gA > 510) ? 510 : gA);
        gB = (gB < 0) ? 0 : ((gB > 510) ? 510 : gB);
        gC = (gC < 0) ? 0 : ((gC > 510) ? 510 : gC);
        float fA = pA - (float)gA, fB = pB - (float)gB, fC = pC - (float)gC;
        int kA = gA * 512, kB = gB * 512, kC = gC * 512;
        #pragma unroll 8
        for (int it = 0; it < 32; ++it) {
            float nwv = nwin[(s0 + 64 + it) * DIM + c];
            {
                float2 tt = *(const float2*)(TTb + lane_bcast_i(kA, it));
                float e = fmaf(lane_bcast_f(fA, it), tt.y - tt.x, tt.x);
                acc0 = fmaf(e, nwv, acc0);
            }
            {
                float2 tt = *(const float2*)(TTb + lane_bcast_i(kB, it));
                float e = fmaf(lane_bcast_f(fB, it), tt.y - tt.x, tt.x);
                acc1 = fmaf(e, nwv, acc1);
            }
            {
                float2 tt = *(const float2*)(TTb + lane_bcast_i(kC, it));
                float e = fmaf(lane_bcast_f(fC, it), tt.y - tt.x, tt.x);
                acc2 = fmaf(e, nwv, acc2);
            }
        }
    }
    s_part[widx][0][c] = acc0;
    s_part[widx][1][c] = acc1;
    s_part[widx][2][c] = acc2;
    __syncthreads();

    if (widx < 3) {
        const int jt = j0 + widx;
        float tot = 0.0f;
        #pragma unroll
        for (int w8 = 0; w8 < 8; ++w8) tot += s_part[w8][widx][c];
        // remove fake i==j term: distT diag=0 -> g=0,f=0 -> e = T[0][c] exactly
        float2 t0 = *(const float2*)TTb;
        tot -= t0.x * nwin[jt * DIM + c];
        // node MLP (wave-local LDS, lockstep)
        float* su = s_upd[widx];
        su[c] = tot;
        float t = qb1[c];
        #pragma unroll 8
        for (int k = 0; k < DIM; ++k) t = fmaf(su[k], qw1[k * DIM + c], t);
        su[64 + c] = softplus05(t);
        float o = qb2[c];
        #pragma unroll 8
        for (int k = 0; k < DIM; ++k) o = fmaf(su[64 + k], qw2[k * DIM + c], o);
        float hn = h[jt * DIM + c] + o;
        h[jt * DIM + c] = hn;
        su[128 + c] = hn;
        if (!last) {
            float v = 0.0f;
            #pragma unroll 8
            for (int k = 0; k < DIM; ++k) v = fmaf(su[128 + k], wnext[k * DIM + c], v);
            nwout[jt * DIM + c] = v;
        } else {
            float t2 = aub1[c];
            #pragma unroll 8
            for (int k = 0; k < DIM; ++k) t2 = fmaf(su[128 + k], auw1[k * DIM + c], t2);
            t2 = ((t2 > 20.0f) ? t2 : __logf(1.0f + __expf(t2))) - LN2F;
            float v = t2 * auw2[c];
            #pragma unroll
            for (int s = 32; s > 0; s >>= 1) v += __shfl_down(v, s, 64);
            if (c == 0) ha[jt] = v + aub2[0];
        }
    }
}

// ============ readout (verified round-5/6 logic) ============
__global__ __launch_bounds__(256)
void k_ro(const float* __restrict__ dist, const int* __restrict__ src,
          const int* __restrict__ dst, const float* __restrict__ ha,
          const float2* __restrict__ TTro,
          const float* __restrict__ row1, const float* __restrict__ row2,
          const float* __restrict__ rob2, float* __restrict__ out) {
    __shared__ float4 s_pre[4][64];
    __shared__ float s_h[4][16 * 65];
    __shared__ float s_w2[128];
    const int tid = threadIdx.x, widx = tid >> 6, c = tid & 63;
    if (tid < 128) s_w2[tid] = row2[tid];
    __syncthreads();
    const int ebase = (blockIdx.x * 4 + widx) * 64;
    {
        int eg = ebase + c;
        float d = dist[eg];
        float pos = d * INVSTEP;
        int kk = (int)pos;
        kk = (kk < 0) ? 0 : ((kk > 510) ? 510 : kk);
        float fa = ha[src[eg]], fb = ha[dst[eg]];
        s_pre[widx][c] = make_float4(__int_as_float(kk * 512), pos - (float)kk, fa, fb);
    }
    const char* TTb2 = (const char*)TTro + c * 8;
    const float wa = row1[c], wb = row1[DIM + c];
    const int e2 = (c >> 1) & 15, p2 = c & 1, kh = c >> 5;
    const float bias2 = (kh == 0) ? rob2[p2] : 0.0f;
    float* sh = s_h[widx];
    #pragma unroll
    for (int ch = 0; ch < 4; ++ch) {
        #pragma unroll 4
        for (int e = 0; e < 16; ++e) {               // lane = channel
            float4 p = s_pre[widx][ch * 16 + e];
            float2 tt = *(const float2*)(TTb2 + __float_as_int(p.x));
            float hv = fmaf(p.y, tt.y - tt.x, tt.x);
            hv = fmaf(p.z, wa, hv);
            hv = fmaf(p.w, wb, hv);
            sh[e * 65 + c] = fmaxf(hv, 0.0f);
        }
        // lane = (khalf, edge, logit); half-k dot then combine
        float lsum = bias2;
        #pragma unroll 8
        for (int k8 = 0; k8 < 32; ++k8) {
            int k = kh * 32 + k8;
            lsum = fmaf(sh[e2 * 65 + k], s_w2[2 * k + p2], lsum);
        }
        lsum += __shfl_xor(lsum, 32, 64);
        float other = __shfl_xor(lsum, 1, 64);
        float m = fmaxf(lsum, other);
        float ea = __expf(lsum - m), eb = __expf(other - m);
        float r = ea / (ea + eb);
        if (c < 32) out[ebase * 2 + ch * 32 + c] = r;
    }
}

extern "C" void kernel_launch(void* const* d_in, const int* in_sizes, int n_in,
                              void* d_out, int out_size, void* d_ws, size_t ws_size,
                              hipStream_t stream) {
    const int*   types = (const int*)d_in[0];
    const float* dist  = (const float*)d_in[1];
    const int*   srcI  = (const int*)d_in[2];
    const int*   dstI  = (const int*)d_in[3];
    const float* emb   = (const float*)d_in[4];
    const float* w1    = (const float*)d_in[5];
    const float* pw1   = (const float*)d_in[6];
    const float* pb1   = (const float*)d_in[7];
    const float* pw2   = (const float*)d_in[8];
    const float* pb2   = (const float*)d_in[9];
    const float* qw1   = (const float*)d_in[10];
    const float* qb1   = (const float*)d_in[11];
    const float* qw2   = (const float*)d_in[12];
    const float* qb2   = (const float*)d_in[13];
    const float* auw1  = (const float*)d_in[14];
    const float* aub1  = (const float*)d_in[15];
    const float* auw2  = (const float*)d_in[16];
    const float* aub2  = (const float*)d_in[17];
    const float* row1  = (const float*)d_in[18];
    const float* rob1  = (const float*)d_in[19];
    const float* row2  = (const float*)d_in[20];
    const float* rob2  = (const float*)d_in[21];

    float* ws   = (float*)d_ws;
    float* outp = (float*)d_out;
    const float2* TT = (const float2*)(ws + WS_TT);
    float* nwbuf[2] = { ws + WS_NWA, ws + WS_NWB };

    k_pre<<<3008, 256, 0, stream>>>(types, dist, emb, w1, pw1, pb1, pw2, pb2,
                                    row1, rob1, ws);
    for (int l = 0; l < 3; ++l) {
        k_edgeupd3<<<256, 512, 0, stream>>>(TT + l * (G * DIM),
            ws + WS_DISTT, nwbuf[l & 1],
            qw1 + l * DIM * DIM, qb1 + l * DIM,
            qw2 + l * DIM * DIM, qb2 + l * DIM,
            ws + WS_H,
            (l < 2) ? (w1 + (l + 1) * DIM * DIM) : w1, nwbuf[(l + 1) & 1],
            auw1, aub1, auw2, aub2, ws + WS_HA, (l == 2) ? 1 : 0);
    }
    k_ro<<<2301, 256, 0, stream>>>(dist, srcI, dstI, ws + WS_HA, TT + 3 * (G * DIM),
                                   row1, row2, rob2, outp);
}

// Round 9
// 191.654 us; speedup vs baseline: 3.4680x; 1.1596x over previous
//
#include <hip/hip_runtime.h>
#include <hip/hip_fp16.h>

#define NATOMS 768
#define NM1    767
#define NEDGE  (768*767)       // 589056
#define DIM    64
#define NC     50
#define GAPF   (5.0f/49.0f)
#define NIGAP  (-49.0f/5.0f)
#define G      512
#define STEPF  (5.0f/511.0f)
#define INVSTEP (511.0f/5.0f)
#define LN2F   0.693147180559945f

// ws layout (float offsets)
#define WS_H     0              // 768*64 f32
#define WS_NWA   49152          // 768*64 f16 (24576 float slots)
#define WS_NWB   73728          // 768*64 f16
#define WS_HA    98304          // 768 f32 (+pad)
#define WS_DISTT 99328          // 768*768 f32
#define WS_TT    689152         // 4 tables * 512*64 __half2 = 131072 float slots

__device__ __forceinline__ float softplus05(float x) {
    float bx = 0.5f * x;
    return (bx > 14.0f) ? x : 2.0f * __logf(1.0f + __expf(bx));
}
__device__ __forceinline__ int lane_bcast_i(int v, int l) {
    return __builtin_amdgcn_readlane(v, l);
}
__device__ __forceinline__ float lane_bcast_f(float v, int l) {
    return __uint_as_float((unsigned)__builtin_amdgcn_readlane((int)__float_as_uint(v), l));
}

// ============ prologue: f16 tables + embed/nw0(f16) + dist transpose ============
__global__ __launch_bounds__(256)
void k_pre(const int* __restrict__ types, const float* __restrict__ dist,
           const float* __restrict__ emb, const float* __restrict__ w1all,
           const float* __restrict__ pw1, const float* __restrict__ pb1,
           const float* __restrict__ pw2, const float* __restrict__ pb2,
           const float* __restrict__ row1, const float* __restrict__ rob1,
           float* __restrict__ ws) {
    __shared__ float s_t[4 * 64];
    const int tid = threadIdx.x, widx = tid >> 6, c = tid & 63;
    float*  h     = ws + WS_H;
    __half* nwh   = (__half*)(ws + WS_NWA);
    float*  distT = ws + WS_DISTT;
    __half* TTh   = (__half*)(ws + WS_TT);
    const int b = blockIdx.x;

    if (b < 512) {
        const int w = b * 4 + widx, tbl = w >> 9, g = w & 511;
        const float d = g * STEPF;
        float val;
        if (tbl < 3) {
            const float* W1 = pw1 + tbl * NC * DIM;
            float t1 = pb1[tbl * DIM + c];
            for (int k = 0; k < NC; ++k) {
                float x = d - GAPF * (float)k;
                t1 = fmaf(__expf(NIGAP * x * x), W1[k * DIM + c], t1);
            }
            s_t[widx * 64 + c] = softplus05(t1);     // wave-local lockstep
            const float* W2 = pw2 + tbl * DIM * DIM;
            val = pb2[tbl * DIM + c];
            #pragma unroll 8
            for (int k = 0; k < DIM; ++k)
                val = fmaf(s_t[widx * 64 + k], W2[k * DIM + c], val);
        } else {
            val = rob1[c];
            for (int k = 0; k < NC; ++k) {
                float x = d - GAPF * (float)k;
                val = fmaf(__expf(NIGAP * x * x), row1[(2 + k) * DIM + c], val);
            }
        }
        // paired f16 layout: entry (g,c) holds (T[g][c], T[g+1][c]) as __half2
        __half* TTt = TTh + tbl * (G * DIM * 2);
        TTt[(g * DIM + c) * 2] = __float2half(val);
        if (g > 0) TTt[((g - 1) * DIM + c) * 2 + 1] = __float2half(val);
    } else if (b < 704) {
        const int i = (b - 512) * 4 + widx;
        float hv = emb[types[i] * DIM + c];
        h[i * DIM + c] = hv;
        s_t[widx * 64 + c] = hv;                     // wave-local
        float acc = 0.0f;
        #pragma unroll 8
        for (int k = 0; k < DIM; ++k)
            acc = fmaf(s_t[widx * 64 + k], w1all[k * DIM + c], acc);
        nwh[i * DIM + c] = __float2half(acc);
    } else {
        const int idx = (b - 704) * 256 + tid;       // < 768*768
        const int j = idx / NATOMS, i = idx - j * NATOMS;
        distT[idx] = (i == j) ? 0.0f : dist[i * NM1 + (j - (j > i))];
    }
}

// ============ conv layer (R6 structure): block owns dest j, f16 table+nw ====
// 768 blocks x 8 waves; wave widx covers sources [widx*96, widx*96+96).
__global__ __launch_bounds__(512)
void k_edgeupd(const __half2* __restrict__ TTl, const float* __restrict__ distT,
               const __half* __restrict__ nwin,
               const float* __restrict__ qw1, const float* __restrict__ qb1,
               const float* __restrict__ qw2, const float* __restrict__ qb2,
               float* __restrict__ h,
               const float* __restrict__ wnext, __half* __restrict__ nwout,
               const float* __restrict__ auw1, const float* __restrict__ aub1,
               const float* __restrict__ auw2, const float* __restrict__ aub2,
               float* __restrict__ ha, int last) {
    __shared__ float s_part[8][64];
    __shared__ float s_upd[192];
    const int tid = threadIdx.x, widx = tid >> 6, c = tid & 63;
    const int j = blockIdx.x;
    const int s0 = widx * 96;

    const char* TTb = (const char*)TTl + c * 4;      // lane's column, 4 B/entry
    float csum = 0.0f;
    { // ---- chunk A: sources s0 .. s0+63, lane c holds (g,f) of s0+c ----
        float d = distT[j * NATOMS + s0 + c];
        float pos = d * INVSTEP;
        int g = (int)pos;
        g = (g < 0) ? 0 : ((g > 510) ? 510 : g);
        float f = pos - (float)g;
        int kx = g * 256;                            // byte offset of f16 row
        #pragma unroll 8
        for (int it = 0; it < 64; ++it) {
            int kxu = lane_bcast_i(kx, it);
            float fu = lane_bcast_f(f, it);
            float2 tt = __half22float2(*(const __half2*)(TTb + kxu));
            float e = fmaf(fu, tt.y - tt.x, tt.x);
            float nwv = __half2float(nwin[(s0 + it) * DIM + c]);
            csum = fmaf(e, nwv, csum);
        }
    }
    { // ---- chunk B: sources s0+64 .. s0+95 (32), lanes mirrored via c&31 ----
        float d = distT[j * NATOMS + s0 + 64 + (c & 31)];
        float pos = d * INVSTEP;
        int g = (int)pos;
        g = (g < 0) ? 0 : ((g > 510) ? 510 : g);
        float f = pos - (float)g;
        int kx = g * 256;
        #pragma unroll 8
        for (int it = 0; it < 32; ++it) {
            int kxu = lane_bcast_i(kx, it);
            float fu = lane_bcast_f(f, it);
            float2 tt = __half22float2(*(const __half2*)(TTb + kxu));
            float e = fmaf(fu, tt.y - tt.x, tt.x);
            float nwv = __half2float(nwin[(s0 + 64 + it) * DIM + c]);
            csum = fmaf(e, nwv, csum);
        }
    }
    s_part[widx][c] = csum;
    __syncthreads();

    if (widx == 0) {
        float tot = 0.0f;
        #pragma unroll
        for (int w8 = 0; w8 < 8; ++w8) tot += s_part[w8][c];
        // remove fake i==j term: distT diag=0 -> g=0,f=0 -> e = T[0][c] exactly
        float2 t0 = __half22float2(*(const __half2*)TTb);
        tot -= t0.x * __half2float(nwin[j * DIM + c]);
        // node MLP (wave-local LDS, lockstep)
        s_upd[c] = tot;
        float t = qb1[c];
        #pragma unroll 8
        for (int k = 0; k < DIM; ++k) t = fmaf(s_upd[k], qw1[k * DIM + c], t);
        s_upd[64 + c] = softplus05(t);
        float o = qb2[c];
        #pragma unroll 8
        for (int k = 0; k < DIM; ++k) o = fmaf(s_upd[64 + k], qw2[k * DIM + c], o);
        float hn = h[j * DIM + c] + o;
        h[j * DIM + c] = hn;
        s_upd[128 + c] = hn;
        if (!last) {
            float v = 0.0f;
            #pragma unroll 8
            for (int k = 0; k < DIM; ++k) v = fmaf(s_upd[128 + k], wnext[k * DIM + c], v);
            nwout[j * DIM + c] = __float2half(v);
        } else {
            float t2 = aub1[c];
            #pragma unroll 8
            for (int k = 0; k < DIM; ++k) t2 = fmaf(s_upd[128 + k], auw1[k * DIM + c], t2);
            t2 = ((t2 > 20.0f) ? t2 : __logf(1.0f + __expf(t2))) - LN2F;
            float v = t2 * auw2[c];
            #pragma unroll
            for (int s = 32; s > 0; s >>= 1) v += __shfl_down(v, s, 64);
            if (c == 0) ha[j] = v + aub2[0];
        }
    }
}

// ============ readout (proven logic, f16 table) ============
__global__ __launch_bounds__(256)
void k_ro(const float* __restrict__ dist, const int* __restrict__ src,
          const int* __restrict__ dst, const float* __restrict__ ha,
          const __half2* __restrict__ TTro,
          const float* __restrict__ row1, const float* __restrict__ row2,
          const float* __restrict__ rob2, float* __restrict__ out) {
    __shared__ float4 s_pre[4][64];
    __shared__ float s_h[4][16 * 65];
    __shared__ float s_w2[128];
    const int tid = threadIdx.x, widx = tid >> 6, c = tid & 63;
    if (tid < 128) s_w2[tid] = row2[tid];
    __syncthreads();
    const int ebase = (blockIdx.x * 4 + widx) * 64;
    {
        int eg = ebase + c;
        float d = dist[eg];
        float pos = d * INVSTEP;
        int kk = (int)pos;
        kk = (kk < 0) ? 0 : ((kk > 510) ? 510 : kk);
        float fa = ha[src[eg]], fb = ha[dst[eg]];
        s_pre[widx][c] = make_float4(__int_as_float(kk * 256), pos - (float)kk, fa, fb);
    }
    const char* TTb2 = (const char*)TTro + c * 4;
    const float wa = row1[c], wb = row1[DIM + c];
    const int e2 = (c >> 1) & 15, p2 = c & 1, kh = c >> 5;
    const float bias2 = (kh == 0) ? rob2[p2] : 0.0f;
    float* sh = s_h[widx];
    #pragma unroll
    for (int ch = 0; ch < 4; ++ch) {
        #pragma unroll 4
        for (int e = 0; e < 16; ++e) {               // lane = channel
            float4 p = s_pre[widx][ch * 16 + e];
            float2 tt = __half22float2(*(const __half2*)(TTb2 + __float_as_int(p.x)));
            float hv = fmaf(p.y, tt.y - tt.x, tt.x);
            hv = fmaf(p.z, wa, hv);
            hv = fmaf(p.w, wb, hv);
            sh[e * 65 + c] = fmaxf(hv, 0.0f);
        }
        // lane = (khalf, edge, logit); half-k dot then combine
        float lsum = bias2;
        #pragma unroll 8
        for (int k8 = 0; k8 < 32; ++k8) {
            int k = kh * 32 + k8;
            lsum = fmaf(sh[e2 * 65 + k], s_w2[2 * k + p2], lsum);
        }
        lsum += __shfl_xor(lsum, 32, 64);
        float other = __shfl_xor(lsum, 1, 64);
        float m = fmaxf(lsum, other);
        float ea = __expf(lsum - m), eb = __expf(other - m);
        float r = ea / (ea + eb);
        if (c < 32) out[ebase * 2 + ch * 32 + c] = r;
    }
}

extern "C" void kernel_launch(void* const* d_in, const int* in_sizes, int n_in,
                              void* d_out, int out_size, void* d_ws, size_t ws_size,
                              hipStream_t stream) {
    const int*   types = (const int*)d_in[0];
    const float* dist  = (const float*)d_in[1];
    const int*   srcI  = (const int*)d_in[2];
    const int*   dstI  = (const int*)d_in[3];
    const float* emb   = (const float*)d_in[4];
    const float* w1    = (const float*)d_in[5];
    const float* pw1   = (const float*)d_in[6];
    const float* pb1   = (const float*)d_in[7];
    const float* pw2   = (const float*)d_in[8];
    const float* pb2   = (const float*)d_in[9];
    const float* qw1   = (const float*)d_in[10];
    const float* qb1   = (const float*)d_in[11];
    const float* qw2   = (const float*)d_in[12];
    const float* qb2   = (const float*)d_in[13];
    const float* auw1  = (const float*)d_in[14];
    const float* aub1  = (const float*)d_in[15];
    const float* auw2  = (const float*)d_in[16];
    const float* aub2  = (const float*)d_in[17];
    const float* row1  = (const float*)d_in[18];
    const float* rob1  = (const float*)d_in[19];
    const float* row2  = (const float*)d_in[20];
    const float* rob2  = (const float*)d_in[21];

    float* ws   = (float*)d_ws;
    float* outp = (float*)d_out;
    const __half2* TT = (const __half2*)(ws + WS_TT);
    __half* nwbuf[2] = { (__half*)(ws + WS_NWA), (__half*)(ws + WS_NWB) };

    k_pre<<<3008, 256, 0, stream>>>(types, dist, emb, w1, pw1, pb1, pw2, pb2,
                                    row1, rob1, ws);
    for (int l = 0; l < 3; ++l) {
        k_edgeupd<<<768, 512, 0, stream>>>(TT + l * (G * DIM),
            ws + WS_DISTT, nwbuf[l & 1],
            qw1 + l * DIM * DIM, qb1 + l * DIM,
            qw2 + l * DIM * DIM, qb2 + l * DIM,
            ws + WS_H,
            (l < 2) ? (w1 + (l + 1) * DIM * DIM) : w1, nwbuf[(l + 1) & 1],
            auw1, aub1, auw2, aub2, ws + WS_HA, (l == 2) ? 1 : 0);
    }
    k_ro<<<2301, 256, 0, stream>>>(dist, srcI, dstI, ws + WS_HA, TT + 3 * (G * DIM),
                                   row1, row2, rob2, outp);
}